// Round 5
// baseline (316.978 us; speedup 1.0000x reference)
//
#include <hip/hip_runtime.h>
#include <hip/hip_bf16.h>

#define NUM_EXPERTS 8
#define MODEL_DIM 1024
#define INTER_DIM 4096
#define BM 128
#define BN 128
#define BK 32

typedef __attribute__((ext_vector_type(8))) short short8;
typedef __attribute__((ext_vector_type(8))) unsigned short ushort8;
typedef __attribute__((ext_vector_type(4))) unsigned short ushort4v;
typedef __attribute__((ext_vector_type(4))) float floatx4;

__device__ __forceinline__ unsigned short f2b(float f) {
  union { float f; unsigned int u; } v; v.f = f;
  unsigned int r = v.u + 0x7fffu + ((v.u >> 16) & 1u);
  return (unsigned short)(r >> 16);
}

// async 16B/lane global->LDS (DMA, no VGPR roundtrip). LDS dest: wave-uniform base + lane*16.
#define GLOAD16(g, l)                                                                   \
  __builtin_amdgcn_global_load_lds((const __attribute__((address_space(1))) unsigned int*)(g), \
                                   (__attribute__((address_space(3))) unsigned int*)(l), 16, 0, 0)

// ---------------- router: top-2 expert ids per token ----------------
__global__ __launch_bounds__(64) void router_kernel(const float* __restrict__ x,
                                                    const float* __restrict__ gw,
                                                    int* __restrict__ eids, int T) {
  int t = blockIdx.x;
  int lane = threadIdx.x;
  float acc[NUM_EXPERTS];
#pragma unroll
  for (int e = 0; e < NUM_EXPERTS; ++e) acc[e] = 0.f;
  const float* xr = x + (size_t)t * MODEL_DIM;
#pragma unroll 4
  for (int i = lane; i < MODEL_DIM; i += 64) {
    float xv = xr[i];
#pragma unroll
    for (int e = 0; e < NUM_EXPERTS; ++e) acc[e] += xv * gw[e * MODEL_DIM + i];
  }
#pragma unroll
  for (int e = 0; e < NUM_EXPERTS; ++e) {
    float v = acc[e];
#pragma unroll
    for (int off = 32; off > 0; off >>= 1) v += __shfl_xor(v, off);
    acc[e] = v;
  }
  if (lane == 0) {
    int e0 = 0; float b0 = acc[0];
#pragma unroll
    for (int e = 1; e < NUM_EXPERTS; ++e) if (acc[e] > b0) { b0 = acc[e]; e0 = e; }
    int e1 = -1; float b1 = -3.4e38f;
#pragma unroll
    for (int e = 0; e < NUM_EXPERTS; ++e) if (e != e0 && acc[e] > b1) { b1 = acc[e]; e1 = e; }
    eids[t] = e0;
    eids[T + t] = e1;
  }
}

__global__ void hist_kernel(const int* __restrict__ eids, int* __restrict__ counts, int total) {
  int i = blockIdx.x * blockDim.x + threadIdx.x;
  if (i < total) atomicAdd(&counts[eids[i]], 1);
}

__global__ void offsets_kernel(const int* __restrict__ counts, int* __restrict__ offsets,
                               int* __restrict__ cursor) {
  if (threadIdx.x == 0 && blockIdx.x == 0) {
    int s = 0;
    for (int e = 0; e < NUM_EXPERTS; ++e) { offsets[e] = s; cursor[e] = s; s += counts[e]; }
    offsets[NUM_EXPERTS] = s;
  }
}

__global__ void scatter_kernel(const int* __restrict__ eids, int* __restrict__ cursor,
                               int* __restrict__ token_list, int T) {
  int i = blockIdx.x * blockDim.x + threadIdx.x;
  if (i < 2 * T) {
    int e = eids[i];
    int pos = atomicAdd(&cursor[e], 1);
    int t = (i >= T) ? (i - T) : i;
    token_list[pos] = t;
  }
}

// ---------------- x -> bf16 (layout preserved) ----------------
__global__ __launch_bounds__(256) void xconv_kernel(const float* __restrict__ X,
                                                    unsigned short* __restrict__ Xb, int n8) {
  int i = blockIdx.x * 256 + threadIdx.x;
  if (i < n8) {
    float4 v0 = *(const float4*)(X + (size_t)i * 8);
    float4 v1 = *(const float4*)(X + (size_t)i * 8 + 4);
    ushort8 s;
    s[0] = f2b(v0.x); s[1] = f2b(v0.y); s[2] = f2b(v0.z); s[3] = f2b(v0.w);
    s[4] = f2b(v1.x); s[5] = f2b(v1.y); s[6] = f2b(v1.z); s[7] = f2b(v1.w);
    *(ushort8*)(Xb + (size_t)i * 8) = s;
  }
}

// ---------------- W [E][K][N] fp32 -> wT [E][N][K] bf16 (LDS 64x64 tile transpose) ----
__global__ __launch_bounds__(256) void wconv_kernel(const float* __restrict__ W,
                                                    unsigned short* __restrict__ O,
                                                    int K, int N) {
  __shared__ unsigned short tile[64 * 68];  // stride 68 shorts: 8B-aligned rows
  const int e = blockIdx.z;
  const int n0 = blockIdx.x * 64;
  const int k0 = blockIdx.y * 64;
  const float* src = W + (size_t)e * K * N;
  unsigned short* dst = O + (size_t)e * N * K;
  const int tid = threadIdx.x;
  {
    const int kr = tid >> 2;            // 0..63
    const int nq = (tid & 3) * 16;      // 0,16,32,48
    const float* p = src + (size_t)(k0 + kr) * N + n0 + nq;
#pragma unroll
    for (int j = 0; j < 4; ++j) {
      float4 v = *(const float4*)(p + j * 4);
      ushort4v s;
      s[0] = f2b(v.x); s[1] = f2b(v.y); s[2] = f2b(v.z); s[3] = f2b(v.w);
      *(ushort4v*)(&tile[kr * 68 + nq + j * 4]) = s;
    }
  }
  __syncthreads();
  {
    const int n = tid >> 2;             // 0..63
    const int ks = (tid & 3) * 16;      // 0,16,32,48
    unsigned short* q = dst + (size_t)(n0 + n) * K + k0 + ks;
#pragma unroll
    for (int c = 0; c < 4; ++c) {
      ushort4v s;
      s[0] = tile[(ks + c * 4 + 0) * 68 + n];
      s[1] = tile[(ks + c * 4 + 1) * 68 + n];
      s[2] = tile[(ks + c * 4 + 2) * 68 + n];
      s[3] = tile[(ks + c * 4 + 3) * 68 + n];
      *(ushort4v*)(q + c * 4) = s;
    }
  }
}

// ---------------- grouped GEMM, m97 structure: global_load_lds + LDS dbuf ----------
// All operands bf16, K-contiguous. UP: A=xb (token gather), B=wupT -> h bf16.
// DOWN: A=h, B=wdnT, split-K=4 -> atomicAdd fp32 Out.
// LDS tiles [128 rows][32 k] linear (64B rows) so gload_lds lane order == layout.
#define STAGE(CUR, KOFS) {                                   \
  GLOAD16(aSrc0 + (KOFS), &sA[CUR][(w * 2 + 0) * 512]);      \
  GLOAD16(aSrc1 + (KOFS), &sA[CUR][(w * 2 + 1) * 512]);      \
  GLOAD16(bSrc0 + (KOFS), &sB[CUR][(w * 2 + 0) * 512]);      \
  GLOAD16(bSrc1 + (KOFS), &sB[CUR][(w * 2 + 1) * 512]);      \
}

template <bool UP>
__global__ __launch_bounds__(256) void moe_gemm(
    const unsigned short* __restrict__ A,    // UP: xb [T][1024]; DOWN: h [4096][4096]
    const unsigned short* __restrict__ Bw,   // wT [E][N][K]
    unsigned short* __restrict__ Hout,       // UP output
    float* __restrict__ Out,                 // DOWN output (atomic)
    const int* __restrict__ offsets,
    const int* __restrict__ token_list) {
  constexpr int K = UP ? MODEL_DIM : INTER_DIM;
  constexpr int NSTEP = 1024 / BK;  // 32 steps per block (UP: full K; DOWN: K/4)

  const int zz = blockIdx.z;
  const int e = UP ? zz : (zz >> 2);
  const int kbeg = UP ? 0 : (zz & 3) * 1024;

  const int off = offsets[e];
  const int cnt = offsets[e + 1] - off;
  const int m0 = blockIdx.y * BM;
  if (m0 >= cnt) return;
  const int n0 = blockIdx.x * BN;

  __shared__ unsigned short sA[2][BM * BK];
  __shared__ unsigned short sB[2][BN * BK];

  const int tid = threadIdx.x;
  const int lane = tid & 63;
  const int w = tid >> 6;
  const int wm = w >> 1, wn = w & 1;
  const int fr = lane & 15;
  const int koff = (lane >> 4) * 8;

  // staging geometry: issue q of wave w covers rows (w*2+q)*16 + (lane>>2), k-chunk (lane&3)*8
  const int lr = lane >> 2;
  const int kq = (lane & 3) * 8;
  const int r0 = (w * 2 + 0) * 16 + lr;
  const int r1 = (w * 2 + 1) * 16 + lr;

  const unsigned short* aSrc0;
  const unsigned short* aSrc1;
  if constexpr (UP) {
    const int c0 = m0 + r0 < cnt ? m0 + r0 : cnt - 1;
    const int c1 = m0 + r1 < cnt ? m0 + r1 : cnt - 1;
    aSrc0 = A + (size_t)token_list[off + c0] * MODEL_DIM + kq;
    aSrc1 = A + (size_t)token_list[off + c1] * MODEL_DIM + kq;
  } else {
    const int c0 = m0 + r0 < cnt ? m0 + r0 : cnt - 1;
    const int c1 = m0 + r1 < cnt ? m0 + r1 : cnt - 1;
    aSrc0 = A + (size_t)(off + c0) * INTER_DIM + kbeg + kq;
    aSrc1 = A + (size_t)(off + c1) * INTER_DIM + kbeg + kq;
  }
  const unsigned short* bBase = Bw + (size_t)e * ((size_t)MODEL_DIM * INTER_DIM);
  const unsigned short* bSrc0 = bBase + (size_t)(n0 + r0) * K + kbeg + kq;
  const unsigned short* bSrc1 = bBase + (size_t)(n0 + r1) * K + kbeg + kq;

  floatx4 acc[4][4];
  const floatx4 zero = {0.f, 0.f, 0.f, 0.f};
#pragma unroll
  for (int i = 0; i < 4; ++i)
#pragma unroll
    for (int j = 0; j < 4; ++j) acc[i][j] = zero;

  STAGE(0, 0)
  __syncthreads();

  int cur = 0;
  for (int s = 0; s < NSTEP; ++s) {
    if (s + 1 < NSTEP) STAGE(cur ^ 1, (s + 1) * BK)  // prefetch next K-step (async DMA)

    short8 a[4], b[4];
#pragma unroll
    for (int i = 0; i < 4; ++i)
      a[i] = *(const short8*)(&sA[cur][(wm * 64 + i * 16 + fr) * BK + koff]);
#pragma unroll
    for (int j = 0; j < 4; ++j)
      b[j] = *(const short8*)(&sB[cur][(wn * 64 + j * 16 + fr) * BK + koff]);
#pragma unroll
    for (int i = 0; i < 4; ++i)
#pragma unroll
      for (int j = 0; j < 4; ++j)
        acc[i][j] = __builtin_amdgcn_mfma_f32_16x16x32_bf16(a[i], b[j], acc[i][j], 0, 0, 0);

    __syncthreads();  // drains vmcnt (staged loads) + all reads of sX[cur] done
    cur ^= 1;
  }

  // epilogue: C/D layout col=lane&15, row=(lane>>4)*4+j
  const int rbase = wm * 64 + (lane >> 4) * 4;
  const int cbase = wn * 64 + fr;
#pragma unroll
  for (int fm = 0; fm < 4; ++fm) {
#pragma unroll
    for (int fn = 0; fn < 4; ++fn) {
#pragma unroll
      for (int j = 0; j < 4; ++j) {
        const int r = rbase + fm * 16 + j;
        const int c = cbase + fn * 16;
        if (m0 + r < cnt) {
          if constexpr (UP) {
            Hout[(size_t)(off + m0 + r) * INTER_DIM + n0 + c] = f2b(acc[fm][fn][j]);
          } else {
            const int t = token_list[off + m0 + r];
            atomicAdd(&Out[(size_t)t * MODEL_DIM + n0 + c], acc[fm][fn][j]);
          }
        }
      }
    }
  }
}

extern "C" void kernel_launch(void* const* d_in, const int* in_sizes, int n_in,
                              void* d_out, int out_size, void* d_ws, size_t ws_size,
                              hipStream_t stream) {
  const float* x = (const float*)d_in[0];
  const float* gw = (const float*)d_in[1];
  const float* w_up = (const float*)d_in[2];
  const float* w_down = (const float*)d_in[3];
  float* out = (float*)d_out;

  const int T = in_sizes[0] / MODEL_DIM;  // 2048
  const int total = 2 * T;                // 4096 routed rows

  char* wsb = (char*)d_ws;
  int* eids = (int*)wsb;            // [total]
  int* counts = eids + total;       // [8]
  int* offsets = counts + 8;        // [9]
  int* cursor = offsets + 12;       // [8]
  int* token_list = cursor + 8;     // [total]
  unsigned short* xb = (unsigned short*)(wsb + (256 << 10));              // 4 MB  [T][1024]
  unsigned short* h  = (unsigned short*)(wsb + (256 << 10) + (4 << 20));  // 32 MB [4096][4096]
  unsigned short* wT = (unsigned short*)(wsb + (256 << 10) + (36 << 20)); // 64 MB shared up/down

  hipMemsetAsync(counts, 0, NUM_EXPERTS * sizeof(int), stream);
  hipMemsetAsync(d_out, 0, (size_t)out_size * sizeof(float), stream);

  xconv_kernel<<<(T * MODEL_DIM / 8 + 255) / 256, 256, 0, stream>>>(x, xb, T * MODEL_DIM / 8);
  router_kernel<<<T, 64, 0, stream>>>(x, gw, eids, T);
  hist_kernel<<<(total + 255) / 256, 256, 0, stream>>>(eids, counts, total);
  offsets_kernel<<<1, 64, 0, stream>>>(counts, offsets, cursor);
  scatter_kernel<<<(total + 255) / 256, 256, 0, stream>>>(eids, cursor, token_list, T);

  // up: convert+transpose W_up [8][1024][4096] -> wT [8][4096][1024], then GEMM
  wconv_kernel<<<dim3(INTER_DIM / 64, MODEL_DIM / 64, NUM_EXPERTS), 256, 0, stream>>>(
      w_up, wT, MODEL_DIM, INTER_DIM);
  moe_gemm<true><<<dim3(INTER_DIM / BN, total / BM, NUM_EXPERTS), 256, 0, stream>>>(
      xb, wT, h, nullptr, offsets, token_list);

  // down: convert+transpose W_down [8][4096][1024] -> wT [8][1024][4096], then GEMM (split-K=4)
  wconv_kernel<<<dim3(MODEL_DIM / 64, INTER_DIM / 64, NUM_EXPERTS), 256, 0, stream>>>(
      w_down, wT, INTER_DIM, MODEL_DIM);
  moe_gemm<false><<<dim3(MODEL_DIM / BN, total / BM, NUM_EXPERTS * 4), 256, 0, stream>>>(
      h, wT, nullptr, out, offsets, token_list);
}